// Round 1
// baseline (2553.104 us; speedup 1.0000x reference)
//
#include <hip/hip_runtime.h>
#include <math.h>
#include <stdint.h>

#define D_DIM   512
#define NCLS    1000
#define KSEL    200
#define NBINS   2048
#define CAND_MAX 1024
#define GCONST  0.005      // 1/(2*sigma^2), sigma=10

// GEMM tiles
#define TM 128
#define TN 128
#define TK 16

// ---------------------------------------------------------------- row norms
__global__ __launch_bounds__(256)
void rownorm_kernel(const float* __restrict__ x, float* __restrict__ out, int rows)
{
    int wave = (int)((blockIdx.x * 256 + threadIdx.x) >> 6);
    int lane = threadIdx.x & 63;
    if (wave >= rows) return;
    const float* r = x + (size_t)wave * D_DIM;
    float s = 0.f;
#pragma unroll
    for (int k = 0; k < D_DIM; k += 64) { float v = r[k + lane]; s += v * v; }
#pragma unroll
    for (int off = 32; off > 0; off >>= 1) s += __shfl_down(s, off, 64);
    if (lane == 0) out[wave] = s;
}

// ---------------------------------------------------------------- dist GEMM
// modes: 0 = histogram only, 1 = histogram + store d2 matrix, 2 = collect
enum { MODE_HIST = 0, MODE_HIST_STORE = 1, MODE_COLLECT = 2 };

template <int MODE>
__global__ __launch_bounds__(256)
void dist_gemm(const float* __restrict__ F, const float* __restrict__ C,
               const float* __restrict__ f2, const float* __restrict__ c2,
               unsigned int* __restrict__ hist, const float* __restrict__ T,
               unsigned int* __restrict__ cnt, int* __restrict__ cand,
               float* __restrict__ d2m, int N)
{
    __shared__ float As[TK][TM];
    __shared__ float Bs[TK][TN];
    const int t  = threadIdx.x;
    const int tx = t & 15;      // 16 col groups of 8
    const int ty = t >> 4;      // 16 row groups of 8
    const int m0 = blockIdx.y * TM;
    const int n0 = blockIdx.x * TN;

    float acc[8][8];
#pragma unroll
    for (int i = 0; i < 8; ++i)
#pragma unroll
        for (int j = 0; j < 8; ++j) acc[i][j] = 0.f;

    for (int k0 = 0; k0 < D_DIM; k0 += TK) {
#pragma unroll
        for (int i = 0; i < 2; ++i) {
            int q   = t + i * 256;       // 0..511
            int row = q >> 2;            // 0..127
            int kq  = (q & 3) << 2;      // 0,4,8,12
            float4 va = *(const float4*)(F + (size_t)(m0 + row) * D_DIM + k0 + kq);
            As[kq + 0][row] = va.x; As[kq + 1][row] = va.y;
            As[kq + 2][row] = va.z; As[kq + 3][row] = va.w;
            int n = n0 + row; if (n > N - 1) n = N - 1;   // clamped (discarded later)
            float4 vb = *(const float4*)(C + (size_t)n * D_DIM + k0 + kq);
            Bs[kq + 0][row] = vb.x; Bs[kq + 1][row] = vb.y;
            Bs[kq + 2][row] = vb.z; Bs[kq + 3][row] = vb.w;
        }
        __syncthreads();
#pragma unroll
        for (int kk = 0; kk < TK; ++kk) {
            float4 a0 = *(const float4*)&As[kk][ty * 8];
            float4 a1 = *(const float4*)&As[kk][ty * 8 + 4];
            float4 b0 = *(const float4*)&Bs[kk][tx * 8];
            float4 b1 = *(const float4*)&Bs[kk][tx * 8 + 4];
            float av[8] = {a0.x, a0.y, a0.z, a0.w, a1.x, a1.y, a1.z, a1.w};
            float bv[8] = {b0.x, b0.y, b0.z, b0.w, b1.x, b1.y, b1.z, b1.w};
#pragma unroll
            for (int i = 0; i < 8; ++i)
#pragma unroll
                for (int j = 0; j < 8; ++j)
                    acc[i][j] = fmaf(av[i], bv[j], acc[i][j]);
        }
        __syncthreads();
    }

    const int rb = m0 + ty * 8;
    const int cb = n0 + tx * 8;
    const bool colok = (cb < N);   // N % 8 == 0 -> whole 8-col group in or out
    float f2r[8], c2r[8];
#pragma unroll
    for (int i = 0; i < 8; ++i) f2r[i] = f2[rb + i];
#pragma unroll
    for (int j = 0; j < 8; ++j) c2r[j] = colok ? c2[cb + j] : 0.f;

    if (MODE == MODE_COLLECT) {
        if (!colok) return;
#pragma unroll
        for (int i = 0; i < 8; ++i) {
            float Tr = T[rb + i];
#pragma unroll
            for (int j = 0; j < 8; ++j) {
                float d2 = f2r[i] + c2r[j] - 2.f * acc[i][j];
                if (d2 <= Tr) {
                    unsigned pos = atomicAdd(&cnt[rb + i], 1u);
                    if (pos < CAND_MAX)
                        cand[(size_t)(rb + i) * CAND_MAX + pos] = cb + j;
                }
            }
        }
    } else {
        if (!colok) return;
#pragma unroll
        for (int i = 0; i < 8; ++i) {
            float d2v[8];
#pragma unroll
            for (int j = 0; j < 8; ++j) d2v[j] = f2r[i] + c2r[j] - 2.f * acc[i][j];
#pragma unroll
            for (int j = 0; j < 8; ++j) {
                int b = (int)(d2v[j] * 0.5f);
                b = b < 0 ? 0 : (b > NBINS - 1 ? NBINS - 1 : b);
                atomicAdd(&hist[(size_t)(rb + i) * NBINS + b], 1u);
            }
            if (MODE == MODE_HIST_STORE) {
                float4 s0 = make_float4(d2v[0], d2v[1], d2v[2], d2v[3]);
                float4 s1 = make_float4(d2v[4], d2v[5], d2v[6], d2v[7]);
                *(float4*)(d2m + (size_t)(rb + i) * N + cb)     = s0;
                *(float4*)(d2m + (size_t)(rb + i) * N + cb + 4) = s1;
            }
        }
    }
}

// ---------------------------------------------------------------- thresholds
__global__ __launch_bounds__(256)
void thresholds_kernel(const unsigned int* __restrict__ hist, float* __restrict__ T)
{
    __shared__ unsigned part[256];
    const int r = blockIdx.x;
    const int t = threadIdx.x;
    unsigned loc[NBINS / 256];
    unsigned s = 0;
#pragma unroll
    for (int i = 0; i < NBINS / 256; ++i) {
        loc[i] = hist[(size_t)r * NBINS + t * (NBINS / 256) + i];
        s += loc[i];
    }
    part[t] = s;
    __syncthreads();
    unsigned pre = 0;
    for (int u = 0; u < t; ++u) pre += part[u];
    if (pre < KSEL && pre + s >= KSEL) {
        unsigned cum = pre;
        int b = NBINS - 1;
#pragma unroll
        for (int i = 0; i < NBINS / 256; ++i) {
            cum += loc[i];
            if (cum >= KSEL) { b = t * (NBINS / 256) + i; break; }
        }
        T[r] = (float)(2 * (b + 1)) + 0.25f;   // bin width 2.0 + safety margin
    }
}

// ---------------------------------------------------------------- collect (store path)
__global__ __launch_bounds__(256)
void collect_scan(const float* __restrict__ d2m, const float* __restrict__ T,
                  unsigned int* __restrict__ cnt, int* __restrict__ cand, int N)
{
    const int r = blockIdx.y;
    const float Tr = T[r];
    int c0 = (blockIdx.x * 256 + threadIdx.x) * 4;
    if (c0 >= N) return;
    float4 v = *(const float4*)(d2m + (size_t)r * N + c0);
    float vv[4] = {v.x, v.y, v.z, v.w};
#pragma unroll
    for (int e = 0; e < 4; ++e) {
        if (vv[e] <= Tr) {
            unsigned pos = atomicAdd(&cnt[r], 1u);
            if (pos < CAND_MAX) cand[(size_t)r * CAND_MAX + pos] = c0 + e;
        }
    }
}

// ---------------------------------------------------------------- finalize
__global__ __launch_bounds__(256)
void finalize_kernel(const float* __restrict__ F, const float* __restrict__ C,
                     const int* __restrict__ labels, const float* __restrict__ weight,
                     const unsigned int* __restrict__ cnt, const int* __restrict__ cand,
                     float* __restrict__ out, int N)
{
    __shared__ float  fs[D_DIM];
    __shared__ double dists[CAND_MAX];
    __shared__ int    idxs[CAND_MAX];
    __shared__ float  p[NCLS];
    __shared__ float  red[256];

    const int r = blockIdx.x;
    const int t = threadIdx.x;
    for (int k = t; k < D_DIM; k += 256) fs[k] = F[(size_t)r * D_DIM + k];
    for (int c = t; c < NCLS; c += 256) p[c] = 0.f;
    int Nc = (int)cnt[r];
    if (Nc > CAND_MAX) Nc = CAND_MAX;
    __syncthreads();

    // exact f64 distances for all candidates
    for (int i = t; i < Nc; i += 256) {
        int ci = cand[(size_t)r * CAND_MAX + i];
        const float* cp = C + (size_t)ci * D_DIM;
        double acc = 0.0;
        for (int k = 0; k < D_DIM; k += 4) {
            float4 v = *(const float4*)(cp + k);
            double d0 = (double)fs[k]     - (double)v.x;
            double d1 = (double)fs[k + 1] - (double)v.y;
            double d2 = (double)fs[k + 2] - (double)v.z;
            double d3 = (double)fs[k + 3] - (double)v.w;
            acc += d0 * d0 + d1 * d1 + d2 * d2 + d3 * d3;
        }
        dists[i] = acc;
        idxs[i]  = ci;
    }
    __syncthreads();

    // exact rank-based top-KSEL (tie-break: lower index, matches lax.top_k)
    int ksel = KSEL < Nc ? KSEL : Nc;
    for (int i = t; i < Nc; i += 256) {
        double di = dists[i];
        int    ii = idxs[i];
        int rank = 0;
        for (int j = 0; j < Nc; ++j) {
            double dj = dists[j];
            rank += (dj < di) || (dj == di && idxs[j] < ii);
        }
        if (rank < ksel) {
            double wgt = exp(-di * GCONST) * exp((double)weight[ii]);
            atomicAdd(&p[labels[ii]], (float)wgt);
        }
    }
    __syncthreads();

    // p==0 -> 1e-10, normalize, log
    float s = 0.f;
    for (int c = t; c < NCLS; c += 256) {
        float v = p[c];
        if (v == 0.f) v = 1e-10f;
        p[c] = v;
        s += v;
    }
    red[t] = s;
    __syncthreads();
    for (int o = 128; o > 0; o >>= 1) {
        if (t < o) red[t] += red[t + o];
        __syncthreads();
    }
    float total = red[0];
    for (int c = t; c < NCLS; c += 256)
        out[(size_t)r * NCLS + c] = logf(p[c] / total);
}

// ---------------------------------------------------------------- launch
extern "C" void kernel_launch(void* const* d_in, const int* in_sizes, int n_in,
                              void* d_out, int out_size, void* d_ws, size_t ws_size,
                              hipStream_t stream)
{
    const float* features = (const float*)d_in[0];
    const float* centres  = (const float*)d_in[1];
    const int*   labels   = (const int*)d_in[2];
    const float* weight   = (const float*)d_in[3];
    const int B = in_sizes[0] / D_DIM;   // 512
    const int N = in_sizes[2];           // 100000
    float* out = (float*)d_out;

    uint8_t* w = (uint8_t*)d_ws;
    size_t off = 0;
    auto alloc = [&](size_t bytes) -> uint8_t* {
        uint8_t* ptr = w + off;
        off = (off + bytes + 255) & ~(size_t)255;
        return ptr;
    };
    float*        f2   = (float*)alloc((size_t)B * 4);
    float*        c2   = (float*)alloc((size_t)N * 4);
    float*        T    = (float*)alloc((size_t)B * 4);
    unsigned int* cnt  = (unsigned int*)alloc((size_t)B * 4);
    unsigned int* hist = (unsigned int*)alloc((size_t)B * NBINS * 4);
    int*          cand = (int*)alloc((size_t)B * CAND_MAX * 4);
    size_t d2m_off = off;
    float* d2m = (float*)(w + d2m_off);
    const bool store = (ws_size >= d2m_off + (size_t)B * N * 4);

    rownorm_kernel<<<(B + 3) / 4, 256, 0, stream>>>(features, f2, B);
    rownorm_kernel<<<(N + 3) / 4, 256, 0, stream>>>(centres, c2, N);
    hipMemsetAsync(hist, 0, (size_t)B * NBINS * 4, stream);
    hipMemsetAsync(cnt, 0, (size_t)B * 4, stream);

    dim3 ggrid((N + TN - 1) / TN, B / TM);
    if (store)
        dist_gemm<MODE_HIST_STORE><<<ggrid, 256, 0, stream>>>(
            features, centres, f2, c2, hist, nullptr, nullptr, nullptr, d2m, N);
    else
        dist_gemm<MODE_HIST><<<ggrid, 256, 0, stream>>>(
            features, centres, f2, c2, hist, nullptr, nullptr, nullptr, nullptr, N);

    thresholds_kernel<<<B, 256, 0, stream>>>(hist, T);

    if (store)
        collect_scan<<<dim3((N / 4 + 255) / 256, B), 256, 0, stream>>>(d2m, T, cnt, cand, N);
    else
        dist_gemm<MODE_COLLECT><<<ggrid, 256, 0, stream>>>(
            features, centres, f2, c2, nullptr, T, cnt, cand, nullptr, N);

    finalize_kernel<<<B, 256, 0, stream>>>(features, centres, labels, weight, cnt, cand, out, N);
}

// Round 2
// 1034.077 us; speedup vs baseline: 2.4690x; 2.4690x over previous
//
#include <hip/hip_runtime.h>
#include <hip/hip_fp16.h>
#include <math.h>
#include <stdint.h>

#define D_DIM    512
#define NCLS     1000
#define KSEL     200
#define NBINS    512          // bin width 4.0, covers d2 in [0, 2048)
#define CAND_MAX 2048
#define GCONST   0.005        // 1/(2*sigma^2), sigma=10
#define MARGIN   2.0f

typedef short s8v __attribute__((ext_vector_type(8)));
typedef float f4v __attribute__((ext_vector_type(4)));

#define GLOAD_LDS16(gp, lp) __builtin_amdgcn_global_load_lds( \
    (const __attribute__((address_space(1))) void*)(gp),      \
    (__attribute__((address_space(3))) void*)(lp), 16, 0, 0)

// RTNE f32 -> bf16 (inputs finite)
static __device__ __forceinline__ unsigned short f2bf(float x) {
    unsigned u = __float_as_uint(x);
    return (unsigned short)((u + 0x7FFFu + ((u >> 16) & 1u)) >> 16);
}

// shared by hist + collect: MUST be bitwise identical in both passes
static __device__ __forceinline__ float d2_from(float f2r, float c2j, __half s) {
    return f2r + c2j - 2.0f * __half2float(s);
}

// ------------------------------------------------- convert F (+ row norms)
__global__ __launch_bounds__(256)
void convertF(const float* __restrict__ F, unsigned short* __restrict__ Fb,
              float* __restrict__ f2)
{
    __shared__ float red[256];
    const int r = blockIdx.x, t = threadIdx.x;
    float2 v = *(const float2*)(F + (size_t)r * D_DIM + t * 2);
    ushort2 o; o.x = f2bf(v.x); o.y = f2bf(v.y);
    *(ushort2*)(Fb + (size_t)r * D_DIM + t * 2) = o;
    red[t] = v.x * v.x + v.y * v.y;
    __syncthreads();
    for (int off = 128; off > 0; off >>= 1) {
        if (t < off) red[t] += red[t + off];
        __syncthreads();
    }
    if (t == 0) f2[r] = red[0];
}

// ------------------------------------------------- convert C (+ row norms)
__global__ __launch_bounds__(256)
void convertC(const float* __restrict__ C, unsigned short* __restrict__ Cb,
              float* __restrict__ c2, int N)
{
    int row  = (int)((blockIdx.x * 256 + threadIdx.x) >> 6);
    int lane = threadIdx.x & 63;
    if (row >= N) return;
    const float* rp = C + (size_t)row * D_DIM;
    float4 a = *(const float4*)(rp + lane * 8);
    float4 b = *(const float4*)(rp + lane * 8 + 4);
    float s = a.x*a.x + a.y*a.y + a.z*a.z + a.w*a.w
            + b.x*b.x + b.y*b.y + b.z*b.z + b.w*b.w;
    uint4 o;
    o.x = (unsigned)f2bf(a.x) | ((unsigned)f2bf(a.y) << 16);
    o.y = (unsigned)f2bf(a.z) | ((unsigned)f2bf(a.w) << 16);
    o.z = (unsigned)f2bf(b.x) | ((unsigned)f2bf(b.y) << 16);
    o.w = (unsigned)f2bf(b.z) | ((unsigned)f2bf(b.w) << 16);
    *(uint4*)(Cb + (size_t)row * D_DIM + lane * 8) = o;
#pragma unroll
    for (int off = 32; off > 0; off >>= 1) s += __shfl_down(s, off, 64);
    if (lane == 0) c2[row] = s;
}

// ------------------------------------------------- MFMA GEMM: S = F * C^T (f16 out)
// 128x128 tile, BK=64, 4 waves (2x2 of 64x64), 16x16x32 bf16 MFMA
__global__ __launch_bounds__(256)
void mfma_gemm(const unsigned short* __restrict__ Fb,
               const unsigned short* __restrict__ Cb,
               __half* __restrict__ Sm, int N)
{
    __shared__ short As[128 * 64];   // [row][k] row-major, 16 KB
    __shared__ short Bs[128 * 64];   // [n][k]   row-major, 16 KB
    const int t    = threadIdx.x;
    const int lane = t & 63;
    const int w    = t >> 6;         // wave 0..3
    const int wm   = w >> 1, wn = w & 1;
    const int m0   = blockIdx.y * 128;
    const int n0   = blockIdx.x * 128;
    const int lrow = lane >> 3;          // 0..7 within staging chunk
    const int lcol = (lane & 7) * 8;     // k octet

    f4v acc[4][4];
#pragma unroll
    for (int i = 0; i < 4; ++i)
#pragma unroll
        for (int j = 0; j < 4; ++j) acc[i][j] = (f4v){0.f, 0.f, 0.f, 0.f};

    const int quad = lane >> 4;      // 0..3
    const int col  = lane & 15;

    for (int k0 = 0; k0 < D_DIM; k0 += 64) {
#pragma unroll
        for (int cc = 0; cc < 4; ++cc) {
            int ch = w * 4 + cc;     // chunk 0..15 = 8 rows each
            const unsigned short* ga =
                Fb + (size_t)(m0 + ch * 8 + lrow) * D_DIM + k0 + lcol;
            GLOAD_LDS16(ga, &As[ch * 512]);
            const unsigned short* gb =
                Cb + (size_t)(n0 + ch * 8 + lrow) * D_DIM + k0 + lcol;
            GLOAD_LDS16(gb, &Bs[ch * 512]);
        }
        __syncthreads();
#pragma unroll
        for (int kk = 0; kk < 2; ++kk) {
            const int kof = kk * 32 + quad * 8;
            s8v a[4], b[4];
#pragma unroll
            for (int i = 0; i < 4; ++i)
                a[i] = *(s8v*)&As[(wm * 64 + i * 16 + col) * 64 + kof];
#pragma unroll
            for (int j = 0; j < 4; ++j)
                b[j] = *(s8v*)&Bs[(wn * 64 + j * 16 + col) * 64 + kof];
#pragma unroll
            for (int i = 0; i < 4; ++i)
#pragma unroll
                for (int j = 0; j < 4; ++j)
                    acc[i][j] = __builtin_amdgcn_mfma_f32_16x16x32_bf16(
                        a[i], b[j], acc[i][j], 0, 0, 0);
        }
        __syncthreads();
    }

    // C/D layout (16x16): col = lane&15, row = quad*4 + reg  [m89 verified]
#pragma unroll
    for (int i = 0; i < 4; ++i) {
        int m = m0 + wm * 64 + i * 16 + quad * 4;
#pragma unroll
        for (int j = 0; j < 4; ++j) {
            int n = n0 + wn * 64 + j * 16 + col;
            if (n < N) {
#pragma unroll
                for (int v = 0; v < 4; ++v)
                    Sm[(size_t)(m + v) * N + n] = __float2half(acc[i][j][v]);
            }
        }
    }
}

// ------------------------------------------------- per-row histogram (LDS)
__global__ __launch_bounds__(256)
void hist_kernel(const __half* __restrict__ Sm, const float* __restrict__ f2,
                 const float* __restrict__ c2, unsigned int* __restrict__ hist,
                 int N)
{
    __shared__ unsigned int h[NBINS];
    const int r = blockIdx.x, t = threadIdx.x;
    for (int b = t; b < NBINS; b += 256) h[b] = 0u;
    __syncthreads();
    const float fr = f2[r];
    const __half* srow = Sm + (size_t)r * N;
    for (int j = t; j < N; j += 256) {
        float d2 = d2_from(fr, c2[j], srow[j]);
        int b = (int)(d2 * 0.25f);
        b = b < 0 ? 0 : (b > NBINS - 1 ? NBINS - 1 : b);
        atomicAdd(&h[b], 1u);
    }
    __syncthreads();
    for (int b = t; b < NBINS; b += 256)
        hist[(size_t)r * NBINS + b] = h[b];     // plain stores, no atomics
}

// ------------------------------------------------- thresholds
__global__ __launch_bounds__(256)
void thresholds_kernel(const unsigned int* __restrict__ hist, float* __restrict__ T)
{
    __shared__ unsigned part[256];
    const int r = blockIdx.x, t = threadIdx.x;
    unsigned loc[NBINS / 256];
    unsigned s = 0;
#pragma unroll
    for (int i = 0; i < NBINS / 256; ++i) {
        loc[i] = hist[(size_t)r * NBINS + t * (NBINS / 256) + i];
        s += loc[i];
    }
    part[t] = s;
    __syncthreads();
    unsigned pre = 0;
    for (int u = 0; u < t; ++u) pre += part[u];
    if (pre < KSEL && pre + s >= KSEL) {
        unsigned cum = pre;
        int b = NBINS - 1;
#pragma unroll
        for (int i = 0; i < NBINS / 256; ++i) {
            cum += loc[i];
            if (cum >= KSEL) { b = t * (NBINS / 256) + i; break; }
        }
        T[r] = 4.0f * (float)(b + 1) + MARGIN;
    }
}

// ------------------------------------------------- collect candidates
__global__ __launch_bounds__(256)
void collect_kernel(const __half* __restrict__ Sm, const float* __restrict__ f2,
                    const float* __restrict__ c2, const float* __restrict__ T,
                    unsigned int* __restrict__ cnt, int* __restrict__ cand, int N)
{
    const int r = blockIdx.y;
    const float Tr = T[r];
    const float fr = f2[r];
    int c0 = (blockIdx.x * 256 + threadIdx.x) * 4;
    if (c0 >= N) return;
    const __half* srow = Sm + (size_t)r * N;
#pragma unroll
    for (int e = 0; e < 4; ++e) {
        int j = c0 + e;
        if (j < N) {
            float d2 = d2_from(fr, c2[j], srow[j]);
            if (d2 <= Tr) {
                unsigned pos = atomicAdd(&cnt[r], 1u);
                if (pos < CAND_MAX) cand[(size_t)r * CAND_MAX + pos] = j;
            }
        }
    }
}

// ------------------------------------------------- finalize (exact f64)
__global__ __launch_bounds__(256)
void finalize_kernel(const float* __restrict__ F, const float* __restrict__ C,
                     const int* __restrict__ labels, const float* __restrict__ weight,
                     const unsigned int* __restrict__ cnt, const int* __restrict__ cand,
                     float* __restrict__ out, int N)
{
    __shared__ float  fs[D_DIM];
    __shared__ double dists[CAND_MAX];
    __shared__ int    idxs[CAND_MAX];
    __shared__ float  p[NCLS];
    __shared__ float  red[256];

    const int r = blockIdx.x;
    const int t = threadIdx.x;
    for (int k = t; k < D_DIM; k += 256) fs[k] = F[(size_t)r * D_DIM + k];
    for (int c = t; c < NCLS; c += 256) p[c] = 0.f;
    int Nc = (int)cnt[r];
    if (Nc > CAND_MAX) Nc = CAND_MAX;
    __syncthreads();

    // exact f64 distances for all candidates
    for (int i = t; i < Nc; i += 256) {
        int ci = cand[(size_t)r * CAND_MAX + i];
        const float* cp = C + (size_t)ci * D_DIM;
        double acc = 0.0;
        for (int k = 0; k < D_DIM; k += 4) {
            float4 v = *(const float4*)(cp + k);
            double d0 = (double)fs[k]     - (double)v.x;
            double d1 = (double)fs[k + 1] - (double)v.y;
            double d2 = (double)fs[k + 2] - (double)v.z;
            double d3 = (double)fs[k + 3] - (double)v.w;
            acc += d0 * d0 + d1 * d1 + d2 * d2 + d3 * d3;
        }
        dists[i] = acc;
        idxs[i]  = ci;
    }
    __syncthreads();

    // exact rank-based top-KSEL (tie-break: lower index, matches lax.top_k)
    int ksel = KSEL < Nc ? KSEL : Nc;
    for (int i = t; i < Nc; i += 256) {
        double di = dists[i];
        int    ii = idxs[i];
        int rank = 0;
        for (int j = 0; j < Nc; ++j) {
            double dj = dists[j];
            rank += (dj < di) || (dj == di && idxs[j] < ii);
        }
        if (rank < ksel) {
            double wgt = exp(-di * GCONST) * exp((double)weight[ii]);
            atomicAdd(&p[labels[ii]], (float)wgt);
        }
    }
    __syncthreads();

    // p==0 -> 1e-10, normalize, log
    float s = 0.f;
    for (int c = t; c < NCLS; c += 256) {
        float v = p[c];
        if (v == 0.f) v = 1e-10f;
        p[c] = v;
        s += v;
    }
    red[t] = s;
    __syncthreads();
    for (int o = 128; o > 0; o >>= 1) {
        if (t < o) red[t] += red[t + o];
        __syncthreads();
    }
    float total = red[0];
    for (int c = t; c < NCLS; c += 256)
        out[(size_t)r * NCLS + c] = logf(p[c] / total);
}

// ------------------------------------------------- launch
extern "C" void kernel_launch(void* const* d_in, const int* in_sizes, int n_in,
                              void* d_out, int out_size, void* d_ws, size_t ws_size,
                              hipStream_t stream)
{
    const float* features = (const float*)d_in[0];
    const float* centres  = (const float*)d_in[1];
    const int*   labels   = (const int*)d_in[2];
    const float* weight   = (const float*)d_in[3];
    const int B = in_sizes[0] / D_DIM;   // 512
    const int N = in_sizes[2];           // 100000
    float* out = (float*)d_out;

    uint8_t* w = (uint8_t*)d_ws;
    size_t off = 0;
    auto alloc = [&](size_t bytes) -> uint8_t* {
        uint8_t* ptr = w + off;
        off = (off + bytes + 255) & ~(size_t)255;
        return ptr;
    };
    float*          f2   = (float*)alloc((size_t)B * 4);
    float*          c2   = (float*)alloc((size_t)N * 4);
    float*          T    = (float*)alloc((size_t)B * 4);
    unsigned int*   cnt  = (unsigned int*)alloc((size_t)B * 4);
    unsigned int*   hist = (unsigned int*)alloc((size_t)B * NBINS * 4);
    int*            cand = (int*)alloc((size_t)B * CAND_MAX * 4);
    unsigned short* Fb   = (unsigned short*)alloc((size_t)B * D_DIM * 2);
    unsigned short* Cb   = (unsigned short*)alloc((size_t)N * D_DIM * 2);
    __half*         Sm   = (__half*)alloc((size_t)B * N * 2);
    (void)ws_size;

    convertF<<<B, 256, 0, stream>>>(features, Fb, f2);
    convertC<<<(N + 3) / 4, 256, 0, stream>>>(centres, Cb, c2, N);
    hipMemsetAsync(cnt, 0, (size_t)B * 4, stream);

    dim3 ggrid((N + 127) / 128, B / 128);
    mfma_gemm<<<ggrid, 256, 0, stream>>>(Fb, Cb, Sm, N);

    hist_kernel<<<B, 256, 0, stream>>>(Sm, f2, c2, hist, N);
    thresholds_kernel<<<B, 256, 0, stream>>>(hist, T);

    dim3 cgrid((N + 1023) / 1024, B);
    collect_kernel<<<cgrid, 256, 0, stream>>>(Sm, f2, c2, T, cnt, cand, N);

    finalize_kernel<<<B, 256, 0, stream>>>(features, centres, labels, weight,
                                           cnt, cand, out, N);
}

// Round 3
// 584.697 us; speedup vs baseline: 4.3665x; 1.7686x over previous
//
#include <hip/hip_runtime.h>
#include <hip/hip_fp16.h>
#include <math.h>
#include <stdint.h>

#define D_DIM    512
#define NCLS     1000
#define KSEL     200
#define NBINS    1024         // bin width 2.0, covers d2 in [0, 2048)
#define CAND_MAX 2048
#define GCONST   0.005        // 1/(2*sigma^2), sigma=10
#define MARGIN   2.0f

typedef short s8v __attribute__((ext_vector_type(8)));
typedef float f4v __attribute__((ext_vector_type(4)));

#define GLOAD_LDS16(gp, lp) __builtin_amdgcn_global_load_lds( \
    (const __attribute__((address_space(1))) void*)(gp),      \
    (__attribute__((address_space(3))) void*)(lp), 16, 0, 0)

// RTNE f32 -> bf16 (inputs finite)
static __device__ __forceinline__ unsigned short f2bf(float x) {
    unsigned u = __float_as_uint(x);
    return (unsigned short)((u + 0x7FFFu + ((u >> 16) & 1u)) >> 16);
}

// ------------------------------------------------- convert F (+ row norms)
__global__ __launch_bounds__(256)
void convertF(const float* __restrict__ F, unsigned short* __restrict__ Fb,
              float* __restrict__ f2)
{
    __shared__ float red[256];
    const int r = blockIdx.x, t = threadIdx.x;
    float2 v = *(const float2*)(F + (size_t)r * D_DIM + t * 2);
    ushort2 o; o.x = f2bf(v.x); o.y = f2bf(v.y);
    *(ushort2*)(Fb + (size_t)r * D_DIM + t * 2) = o;
    red[t] = v.x * v.x + v.y * v.y;
    __syncthreads();
    for (int off = 128; off > 0; off >>= 1) {
        if (t < off) red[t] += red[t + off];
        __syncthreads();
    }
    if (t == 0) f2[r] = red[0];
}

// ------------------------------------------------- convert C (+ row norms)
__global__ __launch_bounds__(256)
void convertC(const float* __restrict__ C, unsigned short* __restrict__ Cb,
              float* __restrict__ c2, int N)
{
    int row  = (int)((blockIdx.x * 256 + threadIdx.x) >> 6);
    int lane = threadIdx.x & 63;
    if (row >= N) return;
    const float* rp = C + (size_t)row * D_DIM;
    float4 a = *(const float4*)(rp + lane * 8);
    float4 b = *(const float4*)(rp + lane * 8 + 4);
    float s = a.x*a.x + a.y*a.y + a.z*a.z + a.w*a.w
            + b.x*b.x + b.y*b.y + b.z*b.z + b.w*b.w;
    uint4 o;
    o.x = (unsigned)f2bf(a.x) | ((unsigned)f2bf(a.y) << 16);
    o.y = (unsigned)f2bf(a.z) | ((unsigned)f2bf(a.w) << 16);
    o.z = (unsigned)f2bf(b.x) | ((unsigned)f2bf(b.y) << 16);
    o.w = (unsigned)f2bf(b.z) | ((unsigned)f2bf(b.w) << 16);
    *(uint4*)(Cb + (size_t)row * D_DIM + lane * 8) = o;
#pragma unroll
    for (int off = 32; off > 0; off >>= 1) s += __shfl_down(s, off, 64);
    if (lane == 0) c2[row] = s;
}

// ------------------------------------------------- MFMA GEMM: S = F * C^T (f16 out)
// 128x128 tile, BK=64, 4 waves (2x2 of 64x64), 16x16x32 bf16 MFMA
__global__ __launch_bounds__(256)
void mfma_gemm(const unsigned short* __restrict__ Fb,
               const unsigned short* __restrict__ Cb,
               __half* __restrict__ Sm, int N)
{
    __shared__ short As[128 * 64];   // [row][k] row-major, 16 KB
    __shared__ short Bs[128 * 64];   // [n][k]   row-major, 16 KB
    const int t    = threadIdx.x;
    const int lane = t & 63;
    const int w    = t >> 6;         // wave 0..3
    const int wm   = w >> 1, wn = w & 1;
    const int m0   = blockIdx.y * 128;
    const int n0   = blockIdx.x * 128;
    const int lrow = lane >> 3;          // 0..7 within staging chunk
    const int lcol = (lane & 7) * 8;     // k octet

    f4v acc[4][4];
#pragma unroll
    for (int i = 0; i < 4; ++i)
#pragma unroll
        for (int j = 0; j < 4; ++j) acc[i][j] = (f4v){0.f, 0.f, 0.f, 0.f};

    const int quad = lane >> 4;      // 0..3
    const int col  = lane & 15;

    for (int k0 = 0; k0 < D_DIM; k0 += 64) {
#pragma unroll
        for (int cc = 0; cc < 4; ++cc) {
            int ch = w * 4 + cc;     // chunk 0..15 = 8 rows each
            const unsigned short* ga =
                Fb + (size_t)(m0 + ch * 8 + lrow) * D_DIM + k0 + lcol;
            GLOAD_LDS16(ga, &As[ch * 512]);
            const unsigned short* gb =
                Cb + (size_t)(n0 + ch * 8 + lrow) * D_DIM + k0 + lcol;
            GLOAD_LDS16(gb, &Bs[ch * 512]);
        }
        __syncthreads();
#pragma unroll
        for (int kk = 0; kk < 2; ++kk) {
            const int kof = kk * 32 + quad * 8;
            s8v a[4], b[4];
#pragma unroll
            for (int i = 0; i < 4; ++i)
                a[i] = *(s8v*)&As[(wm * 64 + i * 16 + col) * 64 + kof];
#pragma unroll
            for (int j = 0; j < 4; ++j)
                b[j] = *(s8v*)&Bs[(wn * 64 + j * 16 + col) * 64 + kof];
#pragma unroll
            for (int i = 0; i < 4; ++i)
#pragma unroll
                for (int j = 0; j < 4; ++j)
                    acc[i][j] = __builtin_amdgcn_mfma_f32_16x16x32_bf16(
                        a[i], b[j], acc[i][j], 0, 0, 0);
        }
        __syncthreads();
    }

    // C/D layout (16x16): col = lane&15, row = quad*4 + reg  [m89 verified]
#pragma unroll
    for (int i = 0; i < 4; ++i) {
        int m = m0 + wm * 64 + i * 16 + quad * 4;
#pragma unroll
        for (int j = 0; j < 4; ++j) {
            int n = n0 + wn * 64 + j * 16 + col;
            if (n < N) {
#pragma unroll
                for (int v = 0; v < 4; ++v)
                    Sm[(size_t)(m + v) * N + n] = __float2half(acc[i][j][v]);
            }
        }
    }
}

// ------------------------------------------------- fused per-row:
// hist -> threshold -> collect -> exact f64 top-K -> class scatter -> log
__global__ __launch_bounds__(256)
void fused_select(const __half* __restrict__ Sm, const float* __restrict__ f2,
                  const float* __restrict__ c2,
                  const float* __restrict__ F, const float* __restrict__ C,
                  const int* __restrict__ labels, const float* __restrict__ weight,
                  float* __restrict__ out, int N)
{
    __shared__ unsigned hist[NBINS];    // 4 KB
    __shared__ float    fs[D_DIM];      // 2 KB
    __shared__ int      idxs[CAND_MAX]; // 8 KB
    __shared__ double   dists[CAND_MAX];// 16 KB
    __shared__ float    p[NCLS];        // 4 KB
    __shared__ float    red[256];
    __shared__ unsigned scanbuf[256];
    __shared__ float    sT;
    __shared__ unsigned scnt;

    const int r = blockIdx.x, t = threadIdx.x;
    for (int b = t; b < NBINS; b += 256) hist[b] = 0u;
    for (int c = t; c < NCLS; c += 256) p[c] = 0.f;
    for (int k = t; k < D_DIM; k += 256) fs[k] = F[(size_t)r * D_DIM + k];
    if (t == 0) { sT = 1e30f; scnt = 0u; }
    __syncthreads();

    const float fr = f2[r];
    const __half* srow = Sm + (size_t)r * N;

    // ---- pass 1: histogram (N % 4 == 0)
    for (int j = t * 4; j < N; j += 1024) {
        float4 cc = *(const float4*)(c2 + j);
        float2 s01 = __half22float2(*(const __half2*)(srow + j));
        float2 s23 = __half22float2(*(const __half2*)(srow + j + 2));
        float d2v[4] = { fr + cc.x - 2.f * s01.x, fr + cc.y - 2.f * s01.y,
                         fr + cc.z - 2.f * s23.x, fr + cc.w - 2.f * s23.y };
#pragma unroll
        for (int e = 0; e < 4; ++e) {
            int b = (int)(d2v[e] * 0.5f);
            b = b < 0 ? 0 : (b > NBINS - 1 ? NBINS - 1 : b);
            atomicAdd(&hist[b], 1u);
        }
    }
    __syncthreads();

    // ---- threshold: blocked cumulative scan, 4 bins / thread
    {
        unsigned loc[NBINS / 256];
        unsigned s = 0;
#pragma unroll
        for (int i = 0; i < NBINS / 256; ++i) {
            loc[i] = hist[t * (NBINS / 256) + i];
            s += loc[i];
        }
        scanbuf[t] = s;
        __syncthreads();
        unsigned pre = 0;
        for (int u = 0; u < t; ++u) pre += scanbuf[u];
        if (pre < KSEL && pre + s >= KSEL) {
            unsigned cum = pre;
            int b = NBINS - 1;
#pragma unroll
            for (int i = 0; i < NBINS / 256; ++i) {
                cum += loc[i];
                if (cum >= KSEL) { b = t * (NBINS / 256) + i; break; }
            }
            sT = 2.0f * (float)(b + 1) + MARGIN;
        }
    }
    __syncthreads();
    const float Tr = sT;

    // ---- pass 2: collect candidate indices (row now L2-hot)
    for (int j = t * 4; j < N; j += 1024) {
        float4 cc = *(const float4*)(c2 + j);
        float2 s01 = __half22float2(*(const __half2*)(srow + j));
        float2 s23 = __half22float2(*(const __half2*)(srow + j + 2));
        float d2v[4] = { fr + cc.x - 2.f * s01.x, fr + cc.y - 2.f * s01.y,
                         fr + cc.z - 2.f * s23.x, fr + cc.w - 2.f * s23.y };
#pragma unroll
        for (int e = 0; e < 4; ++e) {
            if (d2v[e] <= Tr) {
                unsigned pos = atomicAdd(&scnt, 1u);
                if (pos < CAND_MAX) idxs[pos] = j + e;
            }
        }
    }
    __syncthreads();
    int Nc = (int)scnt;
    if (Nc > CAND_MAX) Nc = CAND_MAX;

    // ---- exact f64 distances for candidates
    for (int i = t; i < Nc; i += 256) {
        int ci = idxs[i];
        const float* cp = C + (size_t)ci * D_DIM;
        double acc = 0.0;
        for (int k = 0; k < D_DIM; k += 4) {
            float4 v = *(const float4*)(cp + k);
            double d0 = (double)fs[k]     - (double)v.x;
            double d1 = (double)fs[k + 1] - (double)v.y;
            double d2 = (double)fs[k + 2] - (double)v.z;
            double d3 = (double)fs[k + 3] - (double)v.w;
            acc += d0 * d0 + d1 * d1 + d2 * d2 + d3 * d3;
        }
        dists[i] = acc;
    }
    __syncthreads();

    // ---- exact rank-based top-KSEL (tie-break: lower index, lax.top_k order)
    int ksel = KSEL < Nc ? KSEL : Nc;
    for (int i = t; i < Nc; i += 256) {
        double di = dists[i];
        int    ii = idxs[i];
        int rank = 0;
        for (int j = 0; j < Nc; ++j) {
            double dj = dists[j];
            rank += (dj < di) || (dj == di && idxs[j] < ii);
        }
        if (rank < ksel) {
            double wgt = exp(-di * GCONST) * exp((double)weight[ii]);
            atomicAdd(&p[labels[ii]], (float)wgt);
        }
    }
    __syncthreads();

    // ---- p==0 -> 1e-10, normalize, log
    float s = 0.f;
    for (int c = t; c < NCLS; c += 256) {
        float v = p[c];
        if (v == 0.f) v = 1e-10f;
        p[c] = v;
        s += v;
    }
    red[t] = s;
    __syncthreads();
    for (int o = 128; o > 0; o >>= 1) {
        if (t < o) red[t] += red[t + o];
        __syncthreads();
    }
    float total = red[0];
    for (int c = t; c < NCLS; c += 256)
        out[(size_t)r * NCLS + c] = logf(p[c] / total);
}

// ------------------------------------------------- launch
extern "C" void kernel_launch(void* const* d_in, const int* in_sizes, int n_in,
                              void* d_out, int out_size, void* d_ws, size_t ws_size,
                              hipStream_t stream)
{
    const float* features = (const float*)d_in[0];
    const float* centres  = (const float*)d_in[1];
    const int*   labels   = (const int*)d_in[2];
    const float* weight   = (const float*)d_in[3];
    const int B = in_sizes[0] / D_DIM;   // 512
    const int N = in_sizes[2];           // 100000
    float* out = (float*)d_out;

    uint8_t* w = (uint8_t*)d_ws;
    size_t off = 0;
    auto alloc = [&](size_t bytes) -> uint8_t* {
        uint8_t* ptr = w + off;
        off = (off + bytes + 255) & ~(size_t)255;
        return ptr;
    };
    float*          f2 = (float*)alloc((size_t)B * 4);
    float*          c2 = (float*)alloc((size_t)N * 4);
    unsigned short* Fb = (unsigned short*)alloc((size_t)B * D_DIM * 2);
    unsigned short* Cb = (unsigned short*)alloc((size_t)N * D_DIM * 2);
    __half*         Sm = (__half*)alloc((size_t)B * N * 2);
    (void)ws_size;

    convertF<<<B, 256, 0, stream>>>(features, Fb, f2);
    convertC<<<(N + 3) / 4, 256, 0, stream>>>(centres, Cb, c2, N);

    dim3 ggrid((N + 127) / 128, B / 128);
    mfma_gemm<<<ggrid, 256, 0, stream>>>(Fb, Cb, Sm, N);

    fused_select<<<B, 256, 0, stream>>>(Sm, f2, c2, features, centres,
                                        labels, weight, out, N);
}

// Round 4
// 494.781 us; speedup vs baseline: 5.1601x; 1.1817x over previous
//
#include <hip/hip_runtime.h>
#include <hip/hip_fp16.h>
#include <math.h>
#include <stdint.h>

#define D_DIM    512
#define NCLS     1000
#define KSEL     200
#define NBINS    1024         // bin width 2.0, covers d2 in [0, 2048)
#define CAND_MAX 2048
#define GCONST   0.005        // 1/(2*sigma^2), sigma=10
#define MARGIN   2.0f

typedef short s8v __attribute__((ext_vector_type(8)));
typedef float f4v __attribute__((ext_vector_type(4)));

#define GLOAD_LDS16(gp, lp) __builtin_amdgcn_global_load_lds( \
    (const __attribute__((address_space(1))) void*)(gp),      \
    (__attribute__((address_space(3))) void*)(lp), 16, 0, 0)

// RTNE f32 -> bf16 (inputs finite)
static __device__ __forceinline__ unsigned short f2bf(float x) {
    unsigned u = __float_as_uint(x);
    return (unsigned short)((u + 0x7FFFu + ((u >> 16) & 1u)) >> 16);
}

// ------------------------------------------------- convert F (+ row norms)
__global__ __launch_bounds__(256)
void convertF(const float* __restrict__ F, unsigned short* __restrict__ Fb,
              float* __restrict__ f2)
{
    __shared__ float red[256];
    const int r = blockIdx.x, t = threadIdx.x;
    float2 v = *(const float2*)(F + (size_t)r * D_DIM + t * 2);
    ushort2 o; o.x = f2bf(v.x); o.y = f2bf(v.y);
    *(ushort2*)(Fb + (size_t)r * D_DIM + t * 2) = o;
    red[t] = v.x * v.x + v.y * v.y;
    __syncthreads();
    for (int off = 128; off > 0; off >>= 1) {
        if (t < off) red[t] += red[t + off];
        __syncthreads();
    }
    if (t == 0) f2[r] = red[0];
}

// ------------------------------------------------- convert C (+ row norms), grid-stride
__global__ __launch_bounds__(256)
void convertC(const float* __restrict__ C, unsigned short* __restrict__ Cb,
              float* __restrict__ c2, int N)
{
    const int lane   = threadIdx.x & 63;
    const int wglob  = (int)((blockIdx.x * 256 + threadIdx.x) >> 6);
    const int nwaves = (int)((gridDim.x * 256) >> 6);
    for (int row = wglob; row < N; row += nwaves) {
        const float* rp = C + (size_t)row * D_DIM;
        float4 a = *(const float4*)(rp + lane * 8);
        float4 b = *(const float4*)(rp + lane * 8 + 4);
        float s = a.x*a.x + a.y*a.y + a.z*a.z + a.w*a.w
                + b.x*b.x + b.y*b.y + b.z*b.z + b.w*b.w;
        uint4 o;
        o.x = (unsigned)f2bf(a.x) | ((unsigned)f2bf(a.y) << 16);
        o.y = (unsigned)f2bf(a.z) | ((unsigned)f2bf(a.w) << 16);
        o.z = (unsigned)f2bf(b.x) | ((unsigned)f2bf(b.y) << 16);
        o.w = (unsigned)f2bf(b.z) | ((unsigned)f2bf(b.w) << 16);
        *(uint4*)(Cb + (size_t)row * D_DIM + lane * 8) = o;
#pragma unroll
        for (int off = 32; off > 0; off >>= 1) s += __shfl_down(s, off, 64);
        if (lane == 0) c2[row] = s;
    }
}

// ------------------------------------------------- MFMA GEMM: S = F * C^T (f16 out)
// 128x128 tile, BK=64, 4 waves (2x2 of 64x64), 16x16x32 bf16 MFMA
__global__ __launch_bounds__(256)
void mfma_gemm(const unsigned short* __restrict__ Fb,
               const unsigned short* __restrict__ Cb,
               __half* __restrict__ Sm, int N)
{
    __shared__ short As[128 * 64];   // [row][k] row-major, 16 KB
    __shared__ short Bs[128 * 64];   // [n][k]   row-major, 16 KB
    const int t    = threadIdx.x;
    const int lane = t & 63;
    const int w    = t >> 6;         // wave 0..3
    const int wm   = w >> 1, wn = w & 1;
    const int m0   = blockIdx.y * 128;
    const int n0   = blockIdx.x * 128;
    const int lrow = lane >> 3;          // 0..7 within staging chunk
    const int lcol = (lane & 7) * 8;     // k octet

    f4v acc[4][4];
#pragma unroll
    for (int i = 0; i < 4; ++i)
#pragma unroll
        for (int j = 0; j < 4; ++j) acc[i][j] = (f4v){0.f, 0.f, 0.f, 0.f};

    const int quad = lane >> 4;      // 0..3
    const int col  = lane & 15;

    for (int k0 = 0; k0 < D_DIM; k0 += 64) {
#pragma unroll
        for (int cc = 0; cc < 4; ++cc) {
            int ch = w * 4 + cc;     // chunk 0..15 = 8 rows each
            const unsigned short* ga =
                Fb + (size_t)(m0 + ch * 8 + lrow) * D_DIM + k0 + lcol;
            GLOAD_LDS16(ga, &As[ch * 512]);
            const unsigned short* gb =
                Cb + (size_t)(n0 + ch * 8 + lrow) * D_DIM + k0 + lcol;
            GLOAD_LDS16(gb, &Bs[ch * 512]);
        }
        __syncthreads();
#pragma unroll
        for (int kk = 0; kk < 2; ++kk) {
            const int kof = kk * 32 + quad * 8;
            s8v a[4], b[4];
#pragma unroll
            for (int i = 0; i < 4; ++i)
                a[i] = *(s8v*)&As[(wm * 64 + i * 16 + col) * 64 + kof];
#pragma unroll
            for (int j = 0; j < 4; ++j)
                b[j] = *(s8v*)&Bs[(wn * 64 + j * 16 + col) * 64 + kof];
#pragma unroll
            for (int i = 0; i < 4; ++i)
#pragma unroll
                for (int j = 0; j < 4; ++j)
                    acc[i][j] = __builtin_amdgcn_mfma_f32_16x16x32_bf16(
                        a[i], b[j], acc[i][j], 0, 0, 0);
        }
        __syncthreads();
    }

    // C/D layout (16x16): col = lane&15, row = quad*4 + reg  [m89 verified]
#pragma unroll
    for (int i = 0; i < 4; ++i) {
        int m = m0 + wm * 64 + i * 16 + quad * 4;
#pragma unroll
        for (int j = 0; j < 4; ++j) {
            int n = n0 + wn * 64 + j * 16 + col;
            if (n < N) {
#pragma unroll
                for (int v = 0; v < 4; ++v)
                    Sm[(size_t)(m + v) * N + n] = __float2half(acc[i][j][v]);
            }
        }
    }
}

// ------------------------------------------------- fused per-row (1024 thr):
// hist -> threshold -> collect -> exact f64 top-K -> class scatter -> log
__global__ __launch_bounds__(1024)
void fused_select(const __half* __restrict__ Sm, const float* __restrict__ f2,
                  const float* __restrict__ c2,
                  const float* __restrict__ F, const float* __restrict__ C,
                  const int* __restrict__ labels, const float* __restrict__ weight,
                  float* __restrict__ out, int N)
{
    __shared__ unsigned hist[NBINS];    // 4 KB
    __shared__ float    fs[D_DIM];      // 2 KB
    __shared__ int      idxs[CAND_MAX]; // 8 KB
    __shared__ double   dists[CAND_MAX];// 16 KB
    __shared__ float    p[NCLS];        // 4 KB
    __shared__ float    red[1024];      // 4 KB
    __shared__ unsigned scanbuf[256];
    __shared__ float    sT;
    __shared__ unsigned scnt;

    const int r = blockIdx.x, t = threadIdx.x;
    for (int b = t; b < NBINS; b += 1024) hist[b] = 0u;
    for (int c = t; c < NCLS; c += 1024) p[c] = 0.f;
    for (int k = t; k < D_DIM; k += 1024) fs[k] = F[(size_t)r * D_DIM + k];
    if (t == 0) { sT = 1e30f; scnt = 0u; }
    __syncthreads();

    const float fr = f2[r];
    const __half* srow = Sm + (size_t)r * N;

    // ---- pass 1: histogram (N % 4 == 0)
    for (int j = t * 4; j < N; j += 4096) {
        float4 cc = *(const float4*)(c2 + j);
        float2 s01 = __half22float2(*(const __half2*)(srow + j));
        float2 s23 = __half22float2(*(const __half2*)(srow + j + 2));
        float d2v[4] = { fr + cc.x - 2.f * s01.x, fr + cc.y - 2.f * s01.y,
                         fr + cc.z - 2.f * s23.x, fr + cc.w - 2.f * s23.y };
#pragma unroll
        for (int e = 0; e < 4; ++e) {
            int b = (int)(d2v[e] * 0.5f);
            b = b < 0 ? 0 : (b > NBINS - 1 ? NBINS - 1 : b);
            atomicAdd(&hist[b], 1u);
        }
    }
    __syncthreads();

    // ---- threshold: blocked cumulative scan on first 256 threads
    if (t < 256) {
        unsigned loc[NBINS / 256];
        unsigned s = 0;
#pragma unroll
        for (int i = 0; i < NBINS / 256; ++i) {
            loc[i] = hist[t * (NBINS / 256) + i];
            s += loc[i];
        }
        scanbuf[t] = s;
        __syncthreads();
        unsigned pre = 0;
        for (int u = 0; u < t; ++u) pre += scanbuf[u];
        if (pre < KSEL && pre + s >= KSEL) {
            unsigned cum = pre;
            int b = NBINS - 1;
#pragma unroll
            for (int i = 0; i < NBINS / 256; ++i) {
                cum += loc[i];
                if (cum >= KSEL) { b = t * (NBINS / 256) + i; break; }
            }
            sT = 2.0f * (float)(b + 1) + MARGIN;
        }
    } else {
        __syncthreads();
    }
    __syncthreads();
    const float Tr = sT;

    // ---- pass 2: collect candidate indices (row L2/LLC-hot)
    for (int j = t * 4; j < N; j += 4096) {
        float4 cc = *(const float4*)(c2 + j);
        float2 s01 = __half22float2(*(const __half2*)(srow + j));
        float2 s23 = __half22float2(*(const __half2*)(srow + j + 2));
        float d2v[4] = { fr + cc.x - 2.f * s01.x, fr + cc.y - 2.f * s01.y,
                         fr + cc.z - 2.f * s23.x, fr + cc.w - 2.f * s23.y };
#pragma unroll
        for (int e = 0; e < 4; ++e) {
            if (d2v[e] <= Tr) {
                unsigned pos = atomicAdd(&scnt, 1u);
                if (pos < CAND_MAX) idxs[pos] = j + e;
            }
        }
    }
    __syncthreads();
    int Nc = (int)scnt;
    if (Nc > CAND_MAX) Nc = CAND_MAX;

    // ---- exact f64 distances: one WAVE per candidate, coalesced C gather
    {
        const int wv = t >> 6, lane = t & 63;
        for (int i = wv; i < Nc; i += 16) {
            int ci = idxs[i];
            const float* cp = C + (size_t)ci * D_DIM;
            float4 a  = *(const float4*)(cp + lane * 8);
            float4 b  = *(const float4*)(cp + lane * 8 + 4);
            float4 fa = *(const float4*)(fs + lane * 8);
            float4 fb = *(const float4*)(fs + lane * 8 + 4);
            double d0 = (double)fa.x - (double)a.x;
            double d1 = (double)fa.y - (double)a.y;
            double d2 = (double)fa.z - (double)a.z;
            double d3 = (double)fa.w - (double)a.w;
            double d4 = (double)fb.x - (double)b.x;
            double d5 = (double)fb.y - (double)b.y;
            double d6 = (double)fb.z - (double)b.z;
            double d7 = (double)fb.w - (double)b.w;
            double acc = d0*d0 + d1*d1 + d2*d2 + d3*d3
                       + d4*d4 + d5*d5 + d6*d6 + d7*d7;
#pragma unroll
            for (int off = 32; off > 0; off >>= 1)
                acc += __shfl_down(acc, off, 64);
            if (lane == 0) dists[i] = acc;
        }
    }
    __syncthreads();

    // ---- exact rank-based top-KSEL (tie-break: lower index, lax.top_k order)
    int ksel = KSEL < Nc ? KSEL : Nc;
    for (int i = t; i < Nc; i += 1024) {
        double di = dists[i];
        int    ii = idxs[i];
        int rank = 0;
        for (int j = 0; j < Nc; ++j) {
            double dj = dists[j];
            rank += (dj < di) || (dj == di && idxs[j] < ii);
        }
        if (rank < ksel) {
            double wgt = exp(-di * GCONST) * exp((double)weight[ii]);
            atomicAdd(&p[labels[ii]], (float)wgt);
        }
    }
    __syncthreads();

    // ---- p==0 -> 1e-10, normalize, log
    float s = 0.f;
    for (int c = t; c < NCLS; c += 1024) {
        float v = p[c];
        if (v == 0.f) v = 1e-10f;
        p[c] = v;
        s += v;
    }
    red[t] = s;
    __syncthreads();
    for (int o = 512; o > 0; o >>= 1) {
        if (t < o) red[t] += red[t + o];
        __syncthreads();
    }
    float total = red[0];
    for (int c = t; c < NCLS; c += 1024)
        out[(size_t)r * NCLS + c] = logf(p[c] / total);
}

// ------------------------------------------------- launch
extern "C" void kernel_launch(void* const* d_in, const int* in_sizes, int n_in,
                              void* d_out, int out_size, void* d_ws, size_t ws_size,
                              hipStream_t stream)
{
    const float* features = (const float*)d_in[0];
    const float* centres  = (const float*)d_in[1];
    const int*   labels   = (const int*)d_in[2];
    const float* weight   = (const float*)d_in[3];
    const int B = in_sizes[0] / D_DIM;   // 512
    const int N = in_sizes[2];           // 100000
    float* out = (float*)d_out;

    uint8_t* w = (uint8_t*)d_ws;
    size_t off = 0;
    auto alloc = [&](size_t bytes) -> uint8_t* {
        uint8_t* ptr = w + off;
        off = (off + bytes + 255) & ~(size_t)255;
        return ptr;
    };
    float*          f2 = (float*)alloc((size_t)B * 4);
    float*          c2 = (float*)alloc((size_t)N * 4);
    unsigned short* Fb = (unsigned short*)alloc((size_t)B * D_DIM * 2);
    unsigned short* Cb = (unsigned short*)alloc((size_t)N * D_DIM * 2);
    __half*         Sm = (__half*)alloc((size_t)B * N * 2);
    (void)ws_size;

    convertF<<<B, 256, 0, stream>>>(features, Fb, f2);
    convertC<<<1024, 256, 0, stream>>>(centres, Cb, c2, N);

    dim3 ggrid((N + 127) / 128, B / 128);
    mfma_gemm<<<ggrid, 256, 0, stream>>>(Fb, Cb, Sm, N);

    fused_select<<<B, 1024, 0, stream>>>(Sm, f2, c2, features, centres,
                                         labels, weight, out, N);
}

// Round 5
// 491.311 us; speedup vs baseline: 5.1965x; 1.0071x over previous
//
#include <hip/hip_runtime.h>
#include <hip/hip_fp16.h>
#include <math.h>
#include <stdint.h>

#define D_DIM    512
#define NCLS     1000
#define KSEL     200
#define NBINS    1024         // bin width 2.0, covers d2 in [0, 2048)
#define CAND_MAX 2048
#define GCONST   0.005        // 1/(2*sigma^2), sigma=10
#define MARGIN   2.0f

typedef short s8v __attribute__((ext_vector_type(8)));
typedef float f4v __attribute__((ext_vector_type(4)));

#define GLOAD_LDS16(gp, lp) __builtin_amdgcn_global_load_lds( \
    (const __attribute__((address_space(1))) void*)(gp),      \
    (__attribute__((address_space(3))) void*)(lp), 16, 0, 0)

// RTNE f32 -> bf16 (inputs finite)
static __device__ __forceinline__ unsigned short f2bf(float x) {
    unsigned u = __float_as_uint(x);
    return (unsigned short)((u + 0x7FFFu + ((u >> 16) & 1u)) >> 16);
}

// ------------------------------------------------- convert F (+ row norms)
__global__ __launch_bounds__(256)
void convertF(const float* __restrict__ F, unsigned short* __restrict__ Fb,
              float* __restrict__ f2)
{
    __shared__ float red[256];
    const int r = blockIdx.x, t = threadIdx.x;
    float2 v = *(const float2*)(F + (size_t)r * D_DIM + t * 2);
    ushort2 o; o.x = f2bf(v.x); o.y = f2bf(v.y);
    *(ushort2*)(Fb + (size_t)r * D_DIM + t * 2) = o;
    red[t] = v.x * v.x + v.y * v.y;
    __syncthreads();
    for (int off = 128; off > 0; off >>= 1) {
        if (t < off) red[t] += red[t + off];
        __syncthreads();
    }
    if (t == 0) f2[r] = red[0];
}

// ------------------------------------------------- convert C (+ row norms), grid-stride
__global__ __launch_bounds__(256)
void convertC(const float* __restrict__ C, unsigned short* __restrict__ Cb,
              float* __restrict__ c2, int N)
{
    const int lane   = threadIdx.x & 63;
    const int wglob  = (int)((blockIdx.x * 256 + threadIdx.x) >> 6);
    const int nwaves = (int)((gridDim.x * 256) >> 6);
    for (int row = wglob; row < N; row += nwaves) {
        const float* rp = C + (size_t)row * D_DIM;
        float4 a = *(const float4*)(rp + lane * 8);
        float4 b = *(const float4*)(rp + lane * 8 + 4);
        float s = a.x*a.x + a.y*a.y + a.z*a.z + a.w*a.w
                + b.x*b.x + b.y*b.y + b.z*b.z + b.w*b.w;
        uint4 o;
        o.x = (unsigned)f2bf(a.x) | ((unsigned)f2bf(a.y) << 16);
        o.y = (unsigned)f2bf(a.z) | ((unsigned)f2bf(a.w) << 16);
        o.z = (unsigned)f2bf(b.x) | ((unsigned)f2bf(b.y) << 16);
        o.w = (unsigned)f2bf(b.z) | ((unsigned)f2bf(b.w) << 16);
        *(uint4*)(Cb + (size_t)row * D_DIM + lane * 8) = o;
#pragma unroll
        for (int off = 32; off > 0; off >>= 1) s += __shfl_down(s, off, 64);
        if (lane == 0) c2[row] = s;
    }
}

// ------------------------------------------------- MFMA GEMM: S = F * C^T (f16 out)
// 128x128 tile, BK=64, 4 waves (2x2 of 64x64), 16x16x32 bf16 MFMA.
// LDS k-octets XOR-swizzled by row (kills 16-way ds_read conflicts);
// epilogue packs f16 tile in LDS then stores coalesced uint4.
__global__ __launch_bounds__(256)
void mfma_gemm(const unsigned short* __restrict__ Fb,
               const unsigned short* __restrict__ Cb,
               __half* __restrict__ Sm, int N)
{
    __shared__ short smem[2 * 128 * 64];   // As | Bs, 32 KB; reused as f16 C-tile
    short* As = smem;
    short* Bs = smem + 128 * 64;
    const int t    = threadIdx.x;
    const int lane = t & 63;
    const int w    = t >> 6;         // wave 0..3
    const int wm   = w >> 1, wn = w & 1;
    const int m0   = blockIdx.y * 128;
    const int n0   = blockIdx.x * 128;
    const int lrow = lane >> 3;                       // 0..7 within staging chunk
    const int koct = ((lane & 7) ^ (lrow & 7)) * 8;   // swizzled global k octet

    f4v acc[4][4];
#pragma unroll
    for (int i = 0; i < 4; ++i)
#pragma unroll
        for (int j = 0; j < 4; ++j) acc[i][j] = (f4v){0.f, 0.f, 0.f, 0.f};

    const int quad = lane >> 4;      // 0..3
    const int col  = lane & 15;

    for (int k0 = 0; k0 < D_DIM; k0 += 64) {
#pragma unroll
        for (int cc = 0; cc < 4; ++cc) {
            int ch = w * 4 + cc;     // chunk 0..15 = 8 rows each
            const unsigned short* ga =
                Fb + (size_t)(m0 + ch * 8 + lrow) * D_DIM + k0 + koct;
            GLOAD_LDS16(ga, &As[ch * 512]);
            const unsigned short* gb =
                Cb + (size_t)(n0 + ch * 8 + lrow) * D_DIM + k0 + koct;
            GLOAD_LDS16(gb, &Bs[ch * 512]);
        }
        __syncthreads();
#pragma unroll
        for (int kk = 0; kk < 2; ++kk) {
            s8v a[4], b[4];
#pragma unroll
            for (int i = 0; i < 4; ++i) {
                int row = wm * 64 + i * 16 + col;
                int slot = (kk * 4 + quad) ^ (col & 7);
                a[i] = *(s8v*)&As[row * 64 + slot * 8];
            }
#pragma unroll
            for (int j = 0; j < 4; ++j) {
                int row = wn * 64 + j * 16 + col;
                int slot = (kk * 4 + quad) ^ (col & 7);
                b[j] = *(s8v*)&Bs[row * 64 + slot * 8];
            }
#pragma unroll
            for (int i = 0; i < 4; ++i)
#pragma unroll
                for (int j = 0; j < 4; ++j)
                    acc[i][j] = __builtin_amdgcn_mfma_f32_16x16x32_bf16(
                        a[i], b[j], acc[i][j], 0, 0, 0);
        }
        __syncthreads();
    }

    // ---- epilogue: pack f16 tile into LDS (octet-swizzled), store coalesced
    // C/D layout (16x16): col = lane&15, row = quad*4 + reg  [m89 verified]
    __half* Cs = (__half*)smem;      // 128 x 128 f16 = 32 KB
#pragma unroll
    for (int i = 0; i < 4; ++i) {
#pragma unroll
        for (int j = 0; j < 4; ++j) {
#pragma unroll
            for (int v = 0; v < 4; ++v) {
                int ml = wm * 64 + i * 16 + quad * 4 + v;
                int nl = wn * 64 + j * 16 + col;
                int slot = ((nl >> 3) ^ (ml & 7));
                Cs[ml * 128 + slot * 8 + (nl & 7)] = __float2half(acc[i][j][v]);
            }
        }
    }
    __syncthreads();
#pragma unroll
    for (int it = 0; it < 8; ++it) {
        int idx = it * 256 + t;      // 0..2047
        int row = idx >> 4;          // 0..127
        int oct = idx & 15;          // logical octet within row
        int n   = n0 + oct * 8;
        const __half* src = &Cs[row * 128 + ((oct ^ (row & 7)) * 8)];
        __half* dst = Sm + (size_t)(m0 + row) * N + n;
        if (n + 7 < N) {
            *(uint4*)dst = *(const uint4*)src;
        } else if (n < N) {
            for (int e = 0; e < 8 && n + e < N; ++e) dst[e] = src[e];
        }
    }
}

// ------------------------------------------------- fused per-row (1024 thr):
// hist -> threshold -> collect -> exact f64 top-K -> class scatter -> log
__global__ __launch_bounds__(1024)
void fused_select(const __half* __restrict__ Sm, const float* __restrict__ f2,
                  const float* __restrict__ c2,
                  const float* __restrict__ F, const float* __restrict__ C,
                  const int* __restrict__ labels, const float* __restrict__ weight,
                  float* __restrict__ out, int N)
{
    __shared__ unsigned hist[NBINS];    // 4 KB
    __shared__ float    fs[D_DIM];      // 2 KB
    __shared__ int      idxs[CAND_MAX]; // 8 KB
    __shared__ double   dists[CAND_MAX];// 16 KB
    __shared__ float    p[NCLS];        // 4 KB
    __shared__ float    red[1024];      // 4 KB
    __shared__ unsigned scanbuf[256];
    __shared__ float    sT;
    __shared__ unsigned scnt;

    const int r = blockIdx.x, t = threadIdx.x;
    for (int b = t; b < NBINS; b += 1024) hist[b] = 0u;
    for (int c = t; c < NCLS; c += 1024) p[c] = 0.f;
    for (int k = t; k < D_DIM; k += 1024) fs[k] = F[(size_t)r * D_DIM + k];
    if (t == 0) { sT = 1e30f; scnt = 0u; }
    __syncthreads();

    const float fr = f2[r];
    const __half* srow = Sm + (size_t)r * N;

    // ---- pass 1: histogram, 8 elems/thread/iter (N % 8 == 0)
    for (int j = t * 8; j < N; j += 8192) {
        uint4 sv = *(const uint4*)(srow + j);
        float4 ca = *(const float4*)(c2 + j);
        float4 cb = *(const float4*)(c2 + j + 4);
        float2 s0 = __half22float2(*(__half2*)&sv.x);
        float2 s1 = __half22float2(*(__half2*)&sv.y);
        float2 s2 = __half22float2(*(__half2*)&sv.z);
        float2 s3 = __half22float2(*(__half2*)&sv.w);
        float d2v[8] = { fr + ca.x - 2.f * s0.x, fr + ca.y - 2.f * s0.y,
                         fr + ca.z - 2.f * s1.x, fr + ca.w - 2.f * s1.y,
                         fr + cb.x - 2.f * s2.x, fr + cb.y - 2.f * s2.y,
                         fr + cb.z - 2.f * s3.x, fr + cb.w - 2.f * s3.y };
#pragma unroll
        for (int e = 0; e < 8; ++e) {
            int b = (int)(d2v[e] * 0.5f);
            b = b < 0 ? 0 : (b > NBINS - 1 ? NBINS - 1 : b);
            atomicAdd(&hist[b], 1u);
        }
    }
    __syncthreads();

    // ---- threshold: blocked cumulative scan on first 256 threads
    if (t < 256) {
        unsigned loc[NBINS / 256];
        unsigned s = 0;
#pragma unroll
        for (int i = 0; i < NBINS / 256; ++i) {
            loc[i] = hist[t * (NBINS / 256) + i];
            s += loc[i];
        }
        scanbuf[t] = s;
        __syncthreads();
        unsigned pre = 0;
        for (int u = 0; u < t; ++u) pre += scanbuf[u];
        if (pre < KSEL && pre + s >= KSEL) {
            unsigned cum = pre;
            int b = NBINS - 1;
#pragma unroll
            for (int i = 0; i < NBINS / 256; ++i) {
                cum += loc[i];
                if (cum >= KSEL) { b = t * (NBINS / 256) + i; break; }
            }
            sT = 2.0f * (float)(b + 1) + MARGIN;
        }
    } else {
        __syncthreads();
    }
    __syncthreads();
    const float Tr = sT;

    // ---- pass 2: collect candidate indices (row LLC-hot)
    for (int j = t * 8; j < N; j += 8192) {
        uint4 sv = *(const uint4*)(srow + j);
        float4 ca = *(const float4*)(c2 + j);
        float4 cb = *(const float4*)(c2 + j + 4);
        float2 s0 = __half22float2(*(__half2*)&sv.x);
        float2 s1 = __half22float2(*(__half2*)&sv.y);
        float2 s2 = __half22float2(*(__half2*)&sv.z);
        float2 s3 = __half22float2(*(__half2*)&sv.w);
        float d2v[8] = { fr + ca.x - 2.f * s0.x, fr + ca.y - 2.f * s0.y,
                         fr + ca.z - 2.f * s1.x, fr + ca.w - 2.f * s1.y,
                         fr + cb.x - 2.f * s2.x, fr + cb.y - 2.f * s2.y,
                         fr + cb.z - 2.f * s3.x, fr + cb.w - 2.f * s3.y };
#pragma unroll
        for (int e = 0; e < 8; ++e) {
            if (d2v[e] <= Tr) {
                unsigned pos = atomicAdd(&scnt, 1u);
                if (pos < CAND_MAX) idxs[pos] = j + e;
            }
        }
    }
    __syncthreads();
    int Nc = (int)scnt;
    if (Nc > CAND_MAX) Nc = CAND_MAX;

    // ---- exact f64 distances: one WAVE per candidate, coalesced C gather
    {
        const int wv = t >> 6, lane = t & 63;
        for (int i = wv; i < Nc; i += 16) {
            int ci = idxs[i];
            const float* cp = C + (size_t)ci * D_DIM;
            float4 a  = *(const float4*)(cp + lane * 8);
            float4 b  = *(const float4*)(cp + lane * 8 + 4);
            float4 fa = *(const float4*)(fs + lane * 8);
            float4 fb = *(const float4*)(fs + lane * 8 + 4);
            double d0 = (double)fa.x - (double)a.x;
            double d1 = (double)fa.y - (double)a.y;
            double d2 = (double)fa.z - (double)a.z;
            double d3 = (double)fa.w - (double)a.w;
            double d4 = (double)fb.x - (double)b.x;
            double d5 = (double)fb.y - (double)b.y;
            double d6 = (double)fb.z - (double)b.z;
            double d7 = (double)fb.w - (double)b.w;
            double acc = d0*d0 + d1*d1 + d2*d2 + d3*d3
                       + d4*d4 + d5*d5 + d6*d6 + d7*d7;
#pragma unroll
            for (int off = 32; off > 0; off >>= 1)
                acc += __shfl_down(acc, off, 64);
            if (lane == 0) dists[i] = acc;
        }
    }
    __syncthreads();

    // ---- exact rank-based top-KSEL (tie-break: lower index, lax.top_k order)
    int ksel = KSEL < Nc ? KSEL : Nc;
    for (int i = t; i < Nc; i += 1024) {
        double di = dists[i];
        int    ii = idxs[i];
        int rank = 0;
        for (int j = 0; j < Nc; ++j) {
            double dj = dists[j];
            rank += (dj < di) || (dj == di && idxs[j] < ii);
        }
        if (rank < ksel) {
            double wgt = exp(-di * GCONST) * exp((double)weight[ii]);
            atomicAdd(&p[labels[ii]], (float)wgt);
        }
    }
    __syncthreads();

    // ---- p==0 -> 1e-10, normalize, log
    float s = 0.f;
    for (int c = t; c < NCLS; c += 1024) {
        float v = p[c];
        if (v == 0.f) v = 1e-10f;
        p[c] = v;
        s += v;
    }
    red[t] = s;
    __syncthreads();
    for (int o = 512; o > 0; o >>= 1) {
        if (t < o) red[t] += red[t + o];
        __syncthreads();
    }
    float total = red[0];
    for (int c = t; c < NCLS; c += 1024)
        out[(size_t)r * NCLS + c] = logf(p[c] / total);
}

// ------------------------------------------------- launch
extern "C" void kernel_launch(void* const* d_in, const int* in_sizes, int n_in,
                              void* d_out, int out_size, void* d_ws, size_t ws_size,
                              hipStream_t stream)
{
    const float* features = (const float*)d_in[0];
    const float* centres  = (const float*)d_in[1];
    const int*   labels   = (const int*)d_in[2];
    const float* weight   = (const float*)d_in[3];
    const int B = in_sizes[0] / D_DIM;   // 512
    const int N = in_sizes[2];           // 100000
    float* out = (float*)d_out;

    uint8_t* w = (uint8_t*)d_ws;
    size_t off = 0;
    auto alloc = [&](size_t bytes) -> uint8_t* {
        uint8_t* ptr = w + off;
        off = (off + bytes + 255) & ~(size_t)255;
        return ptr;
    };
    float*          f2 = (float*)alloc((size_t)B * 4);
    float*          c2 = (float*)alloc((size_t)N * 4);
    unsigned short* Fb = (unsigned short*)alloc((size_t)B * D_DIM * 2);
    unsigned short* Cb = (unsigned short*)alloc((size_t)N * D_DIM * 2);
    __half*         Sm = (__half*)alloc((size_t)B * N * 2);
    (void)ws_size;

    convertF<<<B, 256, 0, stream>>>(features, Fb, f2);
    convertC<<<1024, 256, 0, stream>>>(centres, Cb, c2, N);

    dim3 ggrid((N + 127) / 128, B / 128);
    mfma_gemm<<<ggrid, 256, 0, stream>>>(Fb, Cb, Sm, N);

    fused_select<<<B, 1024, 0, stream>>>(Sm, f2, c2, features, centres,
                                         labels, weight, out, N);
}

// Round 6
// 488.790 us; speedup vs baseline: 5.2233x; 1.0052x over previous
//
#include <hip/hip_runtime.h>
#include <hip/hip_fp16.h>
#include <math.h>
#include <stdint.h>

#define D_DIM    512
#define NCLS     1000
#define KSEL     200
#define NBINS    1024         // bin width 2.0, covers d2 in [0, 2048)
#define CAND_MAX 2048
#define GCONST   0.005        // 1/(2*sigma^2), sigma=10
#define MARGIN   2.0f

typedef short s8v __attribute__((ext_vector_type(8)));
typedef float f4v __attribute__((ext_vector_type(4)));

#define GLOAD_LDS16(gp, lp) __builtin_amdgcn_global_load_lds( \
    (const __attribute__((address_space(1))) void*)(gp),      \
    (__attribute__((address_space(3))) void*)(lp), 16, 0, 0)

// RTNE f32 -> bf16 (inputs finite)
static __device__ __forceinline__ unsigned short f2bf(float x) {
    unsigned u = __float_as_uint(x);
    return (unsigned short)((u + 0x7FFFu + ((u >> 16) & 1u)) >> 16);
}

// ------------------------------------------------- convert F (+ row norms)
__global__ __launch_bounds__(256)
void convertF(const float* __restrict__ F, unsigned short* __restrict__ Fb,
              float* __restrict__ f2)
{
    __shared__ float red[256];
    const int r = blockIdx.x, t = threadIdx.x;
    float2 v = *(const float2*)(F + (size_t)r * D_DIM + t * 2);
    ushort2 o; o.x = f2bf(v.x); o.y = f2bf(v.y);
    *(ushort2*)(Fb + (size_t)r * D_DIM + t * 2) = o;
    red[t] = v.x * v.x + v.y * v.y;
    __syncthreads();
    for (int off = 128; off > 0; off >>= 1) {
        if (t < off) red[t] += red[t + off];
        __syncthreads();
    }
    if (t == 0) f2[r] = red[0];
}

// ------------------------------------------------- MFMA GEMM: S = F * C^T (f16 out)
// Fused B-conversion: reads C as f32, converts bf16 in-register, stages to LDS
// (octet-XOR swizzle), computes c2 row norms on the fly (m-block 0 writes them).
// A staged via global_load_lds from Fb. B f32 loads for iter k+1 prefetched
// during iter k's MFMA. Grid is m-fastest so the 4 m-blocks sharing a C
// column-stripe run ~concurrently (LLC catches re-reads).
__global__ __launch_bounds__(256)
void mfma_gemm(const unsigned short* __restrict__ Fb,
               const float* __restrict__ C,
               float* __restrict__ c2g,
               __half* __restrict__ Sm, int N)
{
    __shared__ short smem[2 * 128 * 64];   // As | Bs, 32 KB; reused as f16 C-tile
    short* As = smem;
    short* Bs = smem + 128 * 64;
    const int t    = threadIdx.x;
    const int lane = t & 63;
    const int w    = t >> 6;         // wave 0..3
    const int wm   = w >> 1, wn = w & 1;
    const int m0   = blockIdx.x * 128;   // m fastest (x dim)
    const int n0   = blockIdx.y * 128;
    const int lrow = lane >> 3;          // 0..7 within staging chunk
    const int oct  = (lane & 7) ^ lrow;  // swizzled global k octet
    const int quad = lane >> 4;          // 0..3
    const int col  = lane & 15;

    f4v acc[4][4];
#pragma unroll
    for (int i = 0; i < 4; ++i)
#pragma unroll
        for (int j = 0; j < 4; ++j) acc[i][j] = (f4v){0.f, 0.f, 0.f, 0.f};

    float  c2part[4] = {0.f, 0.f, 0.f, 0.f};
    float4 ra[4], rb[4];

    // preload B f32 for k0 = 0
#pragma unroll
    for (int cc = 0; cc < 4; ++cc) {
        int row = (w * 4 + cc) * 8 + lrow;
        int rg  = n0 + row; rg = rg < N ? rg : N - 1;   // clamp (masked later)
        const float* gp = C + (size_t)rg * D_DIM + oct * 8;
        ra[cc] = *(const float4*)gp;
        rb[cc] = *(const float4*)(gp + 4);
    }

    for (int k0 = 0; k0 < D_DIM; k0 += 64) {
        __syncthreads();             // prev iter's MFMA done with LDS
#pragma unroll
        for (int cc = 0; cc < 4; ++cc) {
            int ch = w * 4 + cc;     // chunk 0..15 = 8 rows each
            GLOAD_LDS16(Fb + (size_t)(m0 + ch * 8 + lrow) * D_DIM + k0 + oct * 8,
                        &As[ch * 512]);
        }
#pragma unroll
        for (int cc = 0; cc < 4; ++cc) {
            int row = (w * 4 + cc) * 8 + lrow;
            float4 va = ra[cc], vb = rb[cc];
            c2part[cc] += va.x*va.x + va.y*va.y + va.z*va.z + va.w*va.w
                        + vb.x*vb.x + vb.y*vb.y + vb.z*vb.z + vb.w*vb.w;
            uint4 o;
            o.x = (unsigned)f2bf(va.x) | ((unsigned)f2bf(va.y) << 16);
            o.y = (unsigned)f2bf(va.z) | ((unsigned)f2bf(va.w) << 16);
            o.z = (unsigned)f2bf(vb.x) | ((unsigned)f2bf(vb.y) << 16);
            o.w = (unsigned)f2bf(vb.z) | ((unsigned)f2bf(vb.w) << 16);
            *(uint4*)&Bs[row * 64 + (lane & 7) * 8] = o;
        }
        __syncthreads();             // As arrived (vmcnt drain) + Bs visible

        if (k0 + 64 < D_DIM) {       // prefetch next B f32 during MFMA
#pragma unroll
            for (int cc = 0; cc < 4; ++cc) {
                int row = (w * 4 + cc) * 8 + lrow;
                int rg  = n0 + row; rg = rg < N ? rg : N - 1;
                const float* gp = C + (size_t)rg * D_DIM + (k0 + 64) + oct * 8;
                ra[cc] = *(const float4*)gp;
                rb[cc] = *(const float4*)(gp + 4);
            }
        }

#pragma unroll
        for (int kk = 0; kk < 2; ++kk) {
            s8v a[4], b[4];
#pragma unroll
            for (int i = 0; i < 4; ++i) {
                int row  = wm * 64 + i * 16 + col;
                int slot = (kk * 4 + quad) ^ (col & 7);
                a[i] = *(s8v*)&As[row * 64 + slot * 8];
            }
#pragma unroll
            for (int j = 0; j < 4; ++j) {
                int row  = wn * 64 + j * 16 + col;
                int slot = (kk * 4 + quad) ^ (col & 7);
                b[j] = *(s8v*)&Bs[row * 64 + slot * 8];
            }
#pragma unroll
            for (int i = 0; i < 4; ++i)
#pragma unroll
                for (int j = 0; j < 4; ++j)
                    acc[i][j] = __builtin_amdgcn_mfma_f32_16x16x32_bf16(
                        a[i], b[j], acc[i][j], 0, 0, 0);
        }
    }

    // ---- c2 row norms: reduce over the 8 lanes sharing each row, m-block 0 writes
#pragma unroll
    for (int cc = 0; cc < 4; ++cc) {
        float s = c2part[cc];
        s += __shfl_xor(s, 1, 64);
        s += __shfl_xor(s, 2, 64);
        s += __shfl_xor(s, 4, 64);
        int row = (w * 4 + cc) * 8 + lrow;
        if (m0 == 0 && (lane & 7) == 0 && (n0 + row) < N)
            c2g[n0 + row] = s;
    }

    // ---- epilogue: pack f16 tile into LDS (octet-swizzled), store coalesced
    // C/D layout (16x16): col = lane&15, row = quad*4 + reg  [m89 verified]
    __syncthreads();                 // last MFMA done before smem reuse
    __half* Cs = (__half*)smem;      // 128 x 128 f16 = 32 KB
#pragma unroll
    for (int i = 0; i < 4; ++i) {
#pragma unroll
        for (int j = 0; j < 4; ++j) {
#pragma unroll
            for (int v = 0; v < 4; ++v) {
                int ml = wm * 64 + i * 16 + quad * 4 + v;
                int nl = wn * 64 + j * 16 + col;
                int slot = ((nl >> 3) ^ (ml & 7));
                Cs[ml * 128 + slot * 8 + (nl & 7)] = __float2half(acc[i][j][v]);
            }
        }
    }
    __syncthreads();
#pragma unroll
    for (int it = 0; it < 8; ++it) {
        int idx = it * 256 + t;      // 0..2047
        int row = idx >> 4;          // 0..127
        int o8  = idx & 15;          // logical octet within row
        int n   = n0 + o8 * 8;
        const __half* src = &Cs[row * 128 + ((o8 ^ (row & 7)) * 8)];
        __half* dst = Sm + (size_t)(m0 + row) * N + n;
        if (n + 7 < N) {
            *(uint4*)dst = *(const uint4*)src;
        } else if (n < N) {
            for (int e = 0; e < 8 && n + e < N; ++e) dst[e] = src[e];
        }
    }
}

// ------------------------------------------------- fused per-row (1024 thr):
// hist -> threshold -> collect -> exact f64 top-K -> class scatter -> log
__global__ __launch_bounds__(1024)
void fused_select(const __half* __restrict__ Sm, const float* __restrict__ f2,
                  const float* __restrict__ c2,
                  const float* __restrict__ F, const float* __restrict__ C,
                  const int* __restrict__ labels, const float* __restrict__ weight,
                  float* __restrict__ out, int N)
{
    __shared__ unsigned hist[NBINS];    // 4 KB
    __shared__ float    fs[D_DIM];      // 2 KB
    __shared__ int      idxs[CAND_MAX]; // 8 KB
    __shared__ double   dists[CAND_MAX];// 16 KB
    __shared__ float    p[NCLS];        // 4 KB
    __shared__ float    red[1024];      // 4 KB
    __shared__ unsigned scanbuf[256];
    __shared__ float    sT;
    __shared__ unsigned scnt;

    const int r = blockIdx.x, t = threadIdx.x;
    for (int b = t; b < NBINS; b += 1024) hist[b] = 0u;
    for (int c = t; c < NCLS; c += 1024) p[c] = 0.f;
    for (int k = t; k < D_DIM; k += 1024) fs[k] = F[(size_t)r * D_DIM + k];
    if (t == 0) { sT = 1e30f; scnt = 0u; }
    __syncthreads();

    const float fr = f2[r];
    const __half* srow = Sm + (size_t)r * N;

    // ---- pass 1: histogram, 8 elems/thread/iter (N % 8 == 0)
    for (int j = t * 8; j < N; j += 8192) {
        uint4 sv = *(const uint4*)(srow + j);
        float4 ca = *(const float4*)(c2 + j);
        float4 cb = *(const float4*)(c2 + j + 4);
        float2 s0 = __half22float2(*(__half2*)&sv.x);
        float2 s1 = __half22float2(*(__half2*)&sv.y);
        float2 s2 = __half22float2(*(__half2*)&sv.z);
        float2 s3 = __half22float2(*(__half2*)&sv.w);
        float d2v[8] = { fr + ca.x - 2.f * s0.x, fr + ca.y - 2.f * s0.y,
                         fr + ca.z - 2.f * s1.x, fr + ca.w - 2.f * s1.y,
                         fr + cb.x - 2.f * s2.x, fr + cb.y - 2.f * s2.y,
                         fr + cb.z - 2.f * s3.x, fr + cb.w - 2.f * s3.y };
#pragma unroll
        for (int e = 0; e < 8; ++e) {
            int b = (int)(d2v[e] * 0.5f);
            b = b < 0 ? 0 : (b > NBINS - 1 ? NBINS - 1 : b);
            atomicAdd(&hist[b], 1u);
        }
    }
    __syncthreads();

    // ---- threshold: blocked cumulative scan on first 256 threads
    if (t < 256) {
        unsigned loc[NBINS / 256];
        unsigned s = 0;
#pragma unroll
        for (int i = 0; i < NBINS / 256; ++i) {
            loc[i] = hist[t * (NBINS / 256) + i];
            s += loc[i];
        }
        scanbuf[t] = s;
        __syncthreads();
        unsigned pre = 0;
        for (int u = 0; u < t; ++u) pre += scanbuf[u];
        if (pre < KSEL && pre + s >= KSEL) {
            unsigned cum = pre;
            int b = NBINS - 1;
#pragma unroll
            for (int i = 0; i < NBINS / 256; ++i) {
                cum += loc[i];
                if (cum >= KSEL) { b = t * (NBINS / 256) + i; break; }
            }
            sT = 2.0f * (float)(b + 1) + MARGIN;
        }
    } else {
        __syncthreads();
    }
    __syncthreads();
    const float Tr = sT;

    // ---- pass 2: collect candidate indices (row LLC-hot)
    for (int j = t * 8; j < N; j += 8192) {
        uint4 sv = *(const uint4*)(srow + j);
        float4 ca = *(const float4*)(c2 + j);
        float4 cb = *(const float4*)(c2 + j + 4);
        float2 s0 = __half22float2(*(__half2*)&sv.x);
        float2 s1 = __half22float2(*(__half2*)&sv.y);
        float2 s2 = __half22float2(*(__half2*)&sv.z);
        float2 s3 = __half22float2(*(__half2*)&sv.w);
        float d2v[8] = { fr + ca.x - 2.f * s0.x, fr + ca.y - 2.f * s0.y,
                         fr + ca.z - 2.f * s1.x, fr + ca.w - 2.f * s1.y,
                         fr + cb.x - 2.f * s2.x, fr + cb.y - 2.f * s2.y,
                         fr + cb.z - 2.f * s3.x, fr + cb.w - 2.f * s3.y };
#pragma unroll
        for (int e = 0; e < 8; ++e) {
            if (d2v[e] <= Tr) {
                unsigned pos = atomicAdd(&scnt, 1u);
                if (pos < CAND_MAX) idxs[pos] = j + e;
            }
        }
    }
    __syncthreads();
    int Nc = (int)scnt;
    if (Nc > CAND_MAX) Nc = CAND_MAX;

    // ---- exact f64 distances: one WAVE per candidate, coalesced C gather
    {
        const int wv = t >> 6, lane = t & 63;
        for (int i = wv; i < Nc; i += 16) {
            int ci = idxs[i];
            const float* cp = C + (size_t)ci * D_DIM;
            float4 a  = *(const float4*)(cp + lane * 8);
            float4 b  = *(const float4*)(cp + lane * 8 + 4);
            float4 fa = *(const float4*)(fs + lane * 8);
            float4 fb = *(const float4*)(fs + lane * 8 + 4);
            double d0 = (double)fa.x - (double)a.x;
            double d1 = (double)fa.y - (double)a.y;
            double d2 = (double)fa.z - (double)a.z;
            double d3 = (double)fa.w - (double)a.w;
            double d4 = (double)fb.x - (double)b.x;
            double d5 = (double)fb.y - (double)b.y;
            double d6 = (double)fb.z - (double)b.z;
            double d7 = (double)fb.w - (double)b.w;
            double acc = d0*d0 + d1*d1 + d2*d2 + d3*d3
                       + d4*d4 + d5*d5 + d6*d6 + d7*d7;
#pragma unroll
            for (int off = 32; off > 0; off >>= 1)
                acc += __shfl_down(acc, off, 64);
            if (lane == 0) dists[i] = acc;
        }
    }
    __syncthreads();

    // ---- exact rank-based top-KSEL (tie-break: lower index, lax.top_k order)
    int ksel = KSEL < Nc ? KSEL : Nc;
    for (int i = t; i < Nc; i += 1024) {
        double di = dists[i];
        int    ii = idxs[i];
        int rank = 0;
        for (int j = 0; j < Nc; ++j) {
            double dj = dists[j];
            rank += (dj < di) || (dj == di && idxs[j] < ii);
        }
        if (rank < ksel) {
            double wgt = exp(-di * GCONST) * exp((double)weight[ii]);
            atomicAdd(&p[labels[ii]], (float)wgt);
        }
    }
    __syncthreads();

    // ---- p==0 -> 1e-10, normalize, log
    float s = 0.f;
    for (int c = t; c < NCLS; c += 1024) {
        float v = p[c];
        if (v == 0.f) v = 1e-10f;
        p[c] = v;
        s += v;
    }
    red[t] = s;
    __syncthreads();
    for (int o = 512; o > 0; o >>= 1) {
        if (t < o) red[t] += red[t + o];
        __syncthreads();
    }
    float total = red[0];
    for (int c = t; c < NCLS; c += 1024)
        out[(size_t)r * NCLS + c] = logf(p[c] / total);
}

// ------------------------------------------------- launch
extern "C" void kernel_launch(void* const* d_in, const int* in_sizes, int n_in,
                              void* d_out, int out_size, void* d_ws, size_t ws_size,
                              hipStream_t stream)
{
    const float* features = (const float*)d_in[0];
    const float* centres  = (const float*)d_in[1];
    const int*   labels   = (const int*)d_in[2];
    const float* weight   = (const float*)d_in[3];
    const int B = in_sizes[0] / D_DIM;   // 512
    const int N = in_sizes[2];           // 100000
    float* out = (float*)d_out;

    uint8_t* w = (uint8_t*)d_ws;
    size_t off = 0;
    auto alloc = [&](size_t bytes) -> uint8_t* {
        uint8_t* ptr = w + off;
        off = (off + bytes + 255) & ~(size_t)255;
        return ptr;
    };
    float*          f2 = (float*)alloc((size_t)B * 4);
    float*          c2 = (float*)alloc((size_t)N * 4);
    unsigned short* Fb = (unsigned short*)alloc((size_t)B * D_DIM * 2);
    __half*         Sm = (__half*)alloc((size_t)B * N * 2);
    (void)ws_size;

    convertF<<<B, 256, 0, stream>>>(features, Fb, f2);

    dim3 ggrid(B / 128, (N + 127) / 128);   // m fastest
    mfma_gemm<<<ggrid, 256, 0, stream>>>(Fb, centres, c2, Sm, N);

    fused_select<<<B, 1024, 0, stream>>>(Sm, f2, c2, features, centres,
                                         labels, weight, out, N);
}